// Round 8
// baseline (86.513 us; speedup 1.0000x reference)
//
#include <hip/hip_runtime.h>

// arDCA: out[n,q] = softmax_q( h[400,q] + sum_{j<400} J[400,q,j,tok(n,j)] )
// R8: barrier-free, LDS-free streaming. Wave = one n-row. Per beat:
//   load 64 consecutive floats (256B coalesced, nontemporal) = 3 cells,
//   __ballot(v>0.5) -> tokens via ctz (one-hot => exactly 1 bit / 21-bit field),
//   one 63-lane gather from L2-hot Jq2 (3 runs of 84B), acc += .
// 133 beats + 1 tail cell per row; shuffle-softmax epilogue. No LDS, no
// barriers, no glds. K0 transposes J slice -> Jq2[ja*21+q] (705 KB).
// N=4096, RES=400, Q=21, L=512.

#define QA    21
#define RESI  400
#define NSEQ  4096
#define JQ2_ELEMS (RESI*QA*QA)   // 176400 floats

// ---------------- K0: Jq2[(j*21+a)*21+q] = J[((8400+q)*512+j)*21+a] --------
__global__ __launch_bounds__(256) void k0_jq2(const float* __restrict__ J,
                                              float* __restrict__ Jq2) {
    int s = blockIdx.x * 256 + threadIdx.x;
    if (s >= JQ2_ELEMS) return;
    int q  = s / 8400;            // 0..20
    int ja = s - q * 8400;        // j*21+a, contiguous -> coalesced read
    Jq2[ja * 21 + q] = J[(8400 + q) * 10752 + ja];
}

// ---------------- K1: ballot-tokenize streaming ----------------------------
// block = 256 thr = 4 waves = 4 rows; grid 1024 -> rows 0..4095 exactly.
__global__ __launch_bounds__(256) void k1_stream(const float* __restrict__ X,
                                                 const float* __restrict__ Jq2,
                                                 const float* __restrict__ h,
                                                 float* __restrict__ out) {
    const int tid = threadIdx.x;
    const int w   = tid >> 6, l = tid & 63;
    const int n   = blockIdx.x * 4 + w;

    const int q = l % 21;                  // lane's q (valid l<63)
    const int g = l / 21;                  // gather group 0..2 (3 for l=63)

    const float* Xr = X + (size_t)n * 8400;
    const char*  Jb = (const char*)Jq2;
    const int laneoff = g * 1764 + (q << 2);   // (g*441 + q)*4 bytes

    float acc = 0.f;

    // main loop: beat i covers row floats [63i, 63i+63) = cells 3i..3i+2.
    // lane63 loads the next beat's first float (in-bounds for i<133) and
    // gathers cell 3i+3 with t2 (valid j<=399, result unused).
    #pragma unroll 7
    for (int i = 0; i < 133; ++i) {
        float v = __builtin_nontemporal_load(&Xr[i * 63 + l]);
        unsigned long long m = __ballot(v > 0.5f);
        unsigned t0 = __builtin_ctz((unsigned)m);          // cell 3i+0, bits 0-20
        unsigned t1 = __builtin_ctz((unsigned)(m >> 21));  // cell 3i+1
        unsigned t2 = __builtin_ctz((unsigned)(m >> 42));  // cell 3i+2
        unsigned ts = (g == 0) ? t0 : ((g == 1) ? t1 : t2);
        int off = i * 5292 + laneoff + (int)ts * 84;       // (3i*441)*4 + ...
        acc += *(const float*)(Jb + off);                  // L2-hot gather
    }
    // tail cell j=399 (row floats 8379..8399), predicated to avoid OOB
    {
        float v = 0.f;
        if (l < 21) v = Xr[8379 + l];
        unsigned long long m = __ballot(v > 0.5f);
        unsigned tt = __builtin_ctz((unsigned)m);
        if (l < 21) acc += *(const float*)(Jb + 703836 + (int)tt * 84 + (l << 2));
    }

    // fold 3 lane-copies: lane l<21 gets acc(l) + acc(l+21) + acc(l+42)
    float a1 = __shfl(acc, l + 21);
    float a2 = __shfl(acc, l + 42);
    float lg = acc + a1 + a2 + h[8400 + q];
    float lv = (l < 21) ? lg : -1e30f;

    // wave-wide softmax over lanes 0..20
    float mx = lv;
    #pragma unroll
    for (int d = 32; d; d >>= 1) mx = fmaxf(mx, __shfl_xor(mx, d));
    float e = (l < 21) ? __expf(lv - mx) : 0.f;
    float s = e;
    #pragma unroll
    for (int d = 32; d; d >>= 1) s += __shfl_xor(s, d);
    if (l < 21) out[n * 21 + l] = e / s;
}

extern "C" void kernel_launch(void* const* d_in, const int* in_sizes, int n_in,
                              void* d_out, int out_size, void* d_ws, size_t ws_size,
                              hipStream_t stream) {
    const float* X = (const float*)d_in[0];   // [4096,400,21] one-hot
    const float* h = (const float*)d_in[1];   // [512,21]
    const float* J = (const float*)d_in[2];   // [512,21,512,21]
    float* out = (float*)d_out;               // [4096,21]

    float* Jq2 = (float*)d_ws;                // 176400 floats (~706 KB)

    k0_jq2<<<(JQ2_ELEMS + 255) / 256, 256, 0, stream>>>(J, Jq2);
    k1_stream<<<NSEQ / 4, 256, 0, stream>>>(X, Jq2, h, out);
}

// Round 9
// 39.121 us; speedup vs baseline: 2.2114x; 2.2114x over previous
//
#include <hip/hip_runtime.h>
#include <hip/hip_bf16.h>

// arDCA: out[n,q] = softmax_q( h[400,q] + sum_{j<400} J[400,q,j,tok(n,j)] )
// R9: dense MFMA GEMM. logits = X[4096 x 8400] * W[8400 x 21],
//   W[k][q] = J[(8400+q)*10752 + k] (k = j*21+a is contiguous in J).
// One-hot X makes this exact; MFMA pipe is idle anyway; the kernel becomes a
// pure register-streamed read of X (copy-ubench pattern: float4 loads, no LDS
// in hot loop, no barriers, no gathers).
// K0: Bt[col(32)][k(8448)] bf16, zero-padded cols>=21 and k>=8400 (540 KB, L2).
// K1: 256 blocks x 512 thr; block = 16 n-rows; 8 waves split K (1056 = 33
//     steps of mfma_f32_16x16x32_bf16 x 2 q-frags); depth-2 reg prefetch;
//     LDS combine + softmax epilogue.
// N=4096, RES=400, Q=21, L=512.

#define QA    21
#define KVAL  8400
#define KPAD  8448               // 8 waves * 33 steps * 32
#define NCOL  32                 // padded q-cols
#define NSEQ  4096

typedef __attribute__((ext_vector_type(4))) float  f32x4;
typedef __attribute__((ext_vector_type(8))) short  bf16x8;

// ---------------- K0: Bt[col*KPAD + k] = bf16(W[k][col]) -------------------
__global__ __launch_bounds__(256) void k0_bt(const float* __restrict__ J,
                                             __hip_bfloat16* __restrict__ Bt) {
    int idx = blockIdx.x * 256 + threadIdx.x;     // 32*8448 = 270336 = 1056*256
    int col = idx / KPAD;
    int k   = idx - col * KPAD;
    float v = 0.f;
    if (col < QA && k < KVAL)
        v = J[(size_t)(8400 + col) * 10752 + k];  // contiguous in k -> coalesced
    Bt[idx] = __float2bfloat16(v);
}

__device__ __forceinline__ short f2bf(float f) {
    __hip_bfloat16 b = __float2bfloat16(f);
    return *reinterpret_cast<short*>(&b);
}

// ---------------- K1: register-streamed MFMA GEMM --------------------------
__global__ __launch_bounds__(512) void k1_mfma(const float* __restrict__ X,
                                               const __hip_bfloat16* __restrict__ Bt,
                                               const float* __restrict__ h,
                                               float* __restrict__ out) {
    __shared__ float part[8][16][32];   // 16 KB: per-wave partial C
    __shared__ float lg[16][32];

    const int tid = threadIdx.x;
    const int w   = tid >> 6;           // 0..7: k-slice
    const int l   = tid & 63;
    const int row = l & 15;             // A: M-row ; B: N-col (same lane field)
    const int kg  = l >> 4;             // 0..3 k-group of 8
    const int n0  = blockIdx.x << 4;    // 16 rows/block, 256 blocks exact

    const int k0 = w * 1056 + kg * 8;   // lane's first k element

    const float* Arow = X + (size_t)(n0 + row) * KVAL;          // row base
    const __hip_bfloat16* Bc0 = Bt + (size_t)row * KPAD + k0;          // cols 0-15
    const __hip_bfloat16* Bc1 = Bt + (size_t)(row + 16) * KPAD + k0;   // cols 16-31

    f32x4  pa0[3], pa1[3];
    bf16x8 pb0[3], pb1[3];
    f32x4  acc0 = {0.f, 0.f, 0.f, 0.f};
    f32x4  acc1 = {0.f, 0.f, 0.f, 0.f};

    // A granule load with tail clamp: k >= 8400 reads row base (finite one-hot
    // data, contribution killed by Bt zero-padding).
    #define LDA(s, g)  (*(const f32x4*)(Arow + (((k0 + (s)*32 + (g)) < KVAL) ? (k0 + (s)*32 + (g)) : 0)))
    #define LDB0(s)    (*(const bf16x8*)(Bc0 + (s)*32))
    #define LDB1(s)    (*(const bf16x8*)(Bc1 + (s)*32))

    // prologue: steps 0,1
    pa0[0] = LDA(0, 0); pa1[0] = LDA(0, 4); pb0[0] = LDB0(0); pb1[0] = LDB1(0);
    pa0[1] = LDA(1, 0); pa1[1] = LDA(1, 4); pb0[1] = LDB0(1); pb1[1] = LDB1(1);

    #pragma unroll
    for (int s = 0; s < 33; ++s) {
        const int sp = s + 2;
        if (sp < 33) {                  // depth-2 prefetch (constant idx: full unroll)
            pa0[sp % 3] = LDA(sp, 0);
            pa1[sp % 3] = LDA(sp, 4);
            pb0[sp % 3] = LDB0(sp);
            pb1[sp % 3] = LDB1(sp);
        }
        const f32x4 a0 = pa0[s % 3], a1 = pa1[s % 3];
        bf16x8 af;
        af[0] = f2bf(a0[0]); af[1] = f2bf(a0[1]);
        af[2] = f2bf(a0[2]); af[3] = f2bf(a0[3]);
        af[4] = f2bf(a1[0]); af[5] = f2bf(a1[1]);
        af[6] = f2bf(a1[2]); af[7] = f2bf(a1[3]);
        acc0 = __builtin_amdgcn_mfma_f32_16x16x32_bf16(af, pb0[s % 3], acc0, 0, 0, 0);
        acc1 = __builtin_amdgcn_mfma_f32_16x16x32_bf16(af, pb1[s % 3], acc1, 0, 0, 0);
    }
    #undef LDA
    #undef LDB0
    #undef LDB1

    // C/D layout: col = lane&15, row = (lane>>4)*4 + reg  [m89-verified]
    #pragma unroll
    for (int r = 0; r < 4; ++r) {
        const int m = (kg << 2) + r;
        part[w][m][row]      = acc0[r];
        part[w][m][row + 16] = acc1[r];
    }
    __syncthreads();

    // combine 8 wave-partials + h ; then softmax over q<21 per row
    {
        const int m = tid >> 5, c = tid & 31;
        float s = 0.f;
        #pragma unroll
        for (int ww = 0; ww < 8; ++ww) s += part[ww][m][c];
        lg[m][c] = s + ((c < QA) ? h[8400 + c] : 0.f);
    }
    __syncthreads();
    {
        const int m = tid >> 5, c = tid & 31;
        if (c < QA) {
            float mx = -1e30f;
            #pragma unroll
            for (int a = 0; a < QA; ++a) mx = fmaxf(mx, lg[m][a]);
            float den = 0.f;
            #pragma unroll
            for (int a = 0; a < QA; ++a) den += __expf(lg[m][a] - mx);
            out[(size_t)(n0 + m) * QA + c] = __expf(lg[m][c] - mx) / den;
        }
    }
}

extern "C" void kernel_launch(void* const* d_in, const int* in_sizes, int n_in,
                              void* d_out, int out_size, void* d_ws, size_t ws_size,
                              hipStream_t stream) {
    const float* X = (const float*)d_in[0];   // [4096,400,21] one-hot fp32
    const float* h = (const float*)d_in[1];   // [512,21]
    const float* J = (const float*)d_in[2];   // [512,21,512,21]
    float* out = (float*)d_out;               // [4096,21]

    __hip_bfloat16* Bt = (__hip_bfloat16*)d_ws;   // 32*8448 bf16 = 540672 B

    k0_bt<<<(NCOL * KPAD) / 256, 256, 0, stream>>>(J, Bt);
    k1_mfma<<<NSEQ / 16, 512, 0, stream>>>(X, Bt, h, out);
}